// Round 2
// baseline (197.923 us; speedup 1.0000x reference)
//
#include <hip/hip_runtime.h>

#define BB 8
#define NN 2048
#define IND 128
#define OUTD 64
#define ALPHA 0.2f
#define TI 16
#define CJ 256

// ---------------- K1: h = x@W, si = h.a1, sj = h.a2 ----------------
__global__ __launch_bounds__(256) void k1_hproj(const float* __restrict__ x,
                                                const float* __restrict__ W,
                                                const float* __restrict__ a,
                                                float* __restrict__ h,
                                                float* __restrict__ si,
                                                float* __restrict__ sj) {
    __shared__ float Wl[IND * OUTD];   // 32 KB = 8192 floats = 2048 float4
    __shared__ float xl[16][IND];      // 8 KB
    int t = threadIdx.x, lane = t & 63, wave = t >> 6;

    // stage W: 2048 float4, 8 per thread
    const float4* W4 = (const float4*)W;
    float4* Wl4 = (float4*)Wl;
    #pragma unroll
    for (int q = 0; q < 8; ++q) Wl4[t + q * 256] = W4[t + q * 256];

    // stage 16 x rows (2048 floats, 512 float4)
    size_t row0 = (size_t)blockIdx.x * 16;
    const float4* x4 = (const float4*)(x + row0 * IND);
    float4* xl4 = (float4*)&xl[0][0];
    xl4[t] = x4[t];
    xl4[t + 256] = x4[t + 256];
    __syncthreads();

    float a1v = a[lane];
    float a2v = a[OUTD + lane];

    float acc[4] = {0.f, 0.f, 0.f, 0.f};
    int rbase = wave * 4;
    for (int k = 0; k < IND; k += 4) {
        float4 xv0 = *(const float4*)&xl[rbase + 0][k];
        float4 xv1 = *(const float4*)&xl[rbase + 1][k];
        float4 xv2 = *(const float4*)&xl[rbase + 2][k];
        float4 xv3 = *(const float4*)&xl[rbase + 3][k];
        #pragma unroll
        for (int q = 0; q < 4; ++q) {
            float w = Wl[(k + q) * OUTD + lane];
            float xq0 = ((const float*)&xv0)[q];
            float xq1 = ((const float*)&xv1)[q];
            float xq2 = ((const float*)&xv2)[q];
            float xq3 = ((const float*)&xv3)[q];
            acc[0] = fmaf(xq0, w, acc[0]);
            acc[1] = fmaf(xq1, w, acc[1]);
            acc[2] = fmaf(xq2, w, acc[2]);
            acc[3] = fmaf(xq3, w, acc[3]);
        }
    }
    #pragma unroll
    for (int rr = 0; rr < 4; ++rr) {
        size_t grow = row0 + rbase + rr;
        h[grow * OUTD + lane] = acc[rr];
        float v1 = acc[rr] * a1v;
        float v2 = acc[rr] * a2v;
        #pragma unroll
        for (int o = 32; o; o >>= 1) {
            v1 += __shfl_xor(v1, o);
            v2 += __shfl_xor(v2, o);
        }
        if (lane == 0) { si[grow] = v1; sj[grow] = v2; }
    }
}

// ---------------- K2: row sums of exp(leaky(si+sj)) over edges + bitmask ----
__global__ __launch_bounds__(256) void k2_sums(const int* __restrict__ adj,
                                               const float* __restrict__ si,
                                               const float* __restrict__ sj,
                                               float* __restrict__ invS,
                                               unsigned char* __restrict__ mask) {
    __shared__ float wsum[4];
    int row = blockIdx.x;            // b*N + i
    int b = row >> 11;               // N = 2048
    int t = threadIdx.x, lane = t & 63, wave = t >> 6;

    float s_i = si[row];
    const int4* arow = (const int4*)(adj + (size_t)row * NN);
    int4 A0 = arow[2 * t];
    int4 A1 = arow[2 * t + 1];
    const float4* sjb = (const float4*)(sj + (size_t)b * NN);
    float4 S0 = sjb[2 * t];
    float4 S1 = sjb[2 * t + 1];

    int av[8] = {A0.x, A0.y, A0.z, A0.w, A1.x, A1.y, A1.z, A1.w};
    float sv[8] = {S0.x, S0.y, S0.z, S0.w, S1.x, S1.y, S1.z, S1.w};

    unsigned m = 0;
    float sum = 0.f;
    #pragma unroll
    for (int q = 0; q < 8; ++q) {
        float e = s_i + sv[q];
        e = e > 0.f ? e : ALPHA * e;
        float p = __expf(e);
        if (av[q] > 0) { m |= (1u << q); sum += p; }
    }
    mask[(size_t)row * 256 + t] = (unsigned char)m;

    #pragma unroll
    for (int o = 32; o; o >>= 1) sum += __shfl_xor(sum, o);
    if (lane == 0) wsum[wave] = sum;
    __syncthreads();
    if (t == 0) {
        float s = wsum[0] + wsum[1] + wsum[2] + wsum[3];
        invS[row] = s > 0.f ? 1.0f / s : 0.f;
    }
}

// ---------------- K3: attention write + h_prime = attn @ h ----------------
__global__ __launch_bounds__(256) void k3_attn_pv(const unsigned char* __restrict__ mask,
                                                  const float* __restrict__ si,
                                                  const float* __restrict__ sj,
                                                  const float* __restrict__ invS,
                                                  const float* __restrict__ h,
                                                  float* __restrict__ attn,
                                                  float* __restrict__ hp) {
    __shared__ float p_lds[TI][CJ];        // 16 KB
    __shared__ float red[4][TI][OUTD];     // 16 KB
    __shared__ float si_s[TI], inv_s[TI];

    int t = threadIdx.x;
    int blk = blockIdx.x;                  // B * (N/TI)
    int b = blk / (NN / TI);
    int i0 = (blk % (NN / TI)) * TI;
    size_t rowbase = (size_t)b * NN + i0;

    if (t < TI) {
        si_s[t] = si[rowbase + t];
        inv_s[t] = invS[rowbase + t];
    }
    __syncthreads();

    float acc[TI];
    #pragma unroll
    for (int r = 0; r < TI; ++r) acc[r] = 0.f;

    int d = t & 63, g = t >> 6;

    for (int c = 0; c < NN / CJ; ++c) {
        int j = c * CJ + t;
        float sjv = sj[(size_t)b * NN + j];
        int mbyte_off = j >> 3;
        int mbit = j & 7;
        #pragma unroll
        for (int r = 0; r < TI; ++r) {
            unsigned char mb = mask[(rowbase + r) * 256 + mbyte_off];
            float e = si_s[r] + sjv;
            e = e > 0.f ? e : ALPHA * e;
            float p = ((mb >> mbit) & 1) ? __expf(e) * inv_s[r] : 0.f;
            attn[(rowbase + r) * (size_t)NN + j] = p;
            p_lds[r][t] = p;
        }
        __syncthreads();

        // PV: group g handles j-subrange [g*64, g*64+64), lane d = output dim
        const float* hb = h + ((size_t)b * NN + (size_t)c * CJ + g * 64) * OUTD + d;
        #pragma unroll 4
        for (int k4 = 0; k4 < 16; ++k4) {
            float hv0 = hb[(k4 * 4 + 0) * OUTD];
            float hv1 = hb[(k4 * 4 + 1) * OUTD];
            float hv2 = hb[(k4 * 4 + 2) * OUTD];
            float hv3 = hb[(k4 * 4 + 3) * OUTD];
            #pragma unroll
            for (int r = 0; r < TI; ++r) {
                float4 pv = *(const float4*)&p_lds[r][g * 64 + k4 * 4];
                acc[r] = fmaf(pv.x, hv0, acc[r]);
                acc[r] = fmaf(pv.y, hv1, acc[r]);
                acc[r] = fmaf(pv.z, hv2, acc[r]);
                acc[r] = fmaf(pv.w, hv3, acc[r]);
            }
        }
        __syncthreads();
    }

    // cross-group reduce (4 partials per (r,d))
    #pragma unroll
    for (int r = 0; r < TI; ++r) red[g][r][d] = acc[r];
    __syncthreads();
    for (int idx = t; idx < TI * OUTD; idx += 256) {
        int r = idx >> 6, dd = idx & 63;
        float v = red[0][r][dd] + red[1][r][dd] + red[2][r][dd] + red[3][r][dd];
        hp[(rowbase + r) * OUTD + dd] = v;
    }
}

extern "C" void kernel_launch(void* const* d_in, const int* in_sizes, int n_in,
                              void* d_out, int out_size, void* d_ws, size_t ws_size,
                              hipStream_t stream) {
    const float* x   = (const float*)d_in[0];
    const int*   adj = (const int*)d_in[1];
    const float* W   = (const float*)d_in[2];
    const float* a   = (const float*)d_in[3];

    float* out  = (float*)d_out;
    float* hp   = out;                                  // (B,N,OUT)
    float* attn = out + (size_t)BB * NN * OUTD;         // (B,N,N)

    char* ws = (char*)d_ws;
    float* h    = (float*)ws;                           // B*N*OUT floats (4 MB)
    float* si   = h + (size_t)BB * NN * OUTD;           // B*N
    float* sj   = si + (size_t)BB * NN;                 // B*N
    float* invS = sj + (size_t)BB * NN;                 // B*N
    unsigned char* mask = (unsigned char*)(invS + (size_t)BB * NN);  // B*N*256 bytes (4 MB)

    k1_hproj<<<BB * NN / 16, 256, 0, stream>>>(x, W, a, h, si, sj);
    k2_sums<<<BB * NN, 256, 0, stream>>>(adj, si, sj, invS, mask);
    k3_attn_pv<<<BB * (NN / TI), 256, 0, stream>>>(mask, si, sj, invS, h, attn, hp);
}

// Round 3
// 182.335 us; speedup vs baseline: 1.0855x; 1.0855x over previous
//
#include <hip/hip_runtime.h>

#define BB 8
#define NN 2048
#define IND 128
#define OUTD 64
#define ALPHA 0.2f
#define TI 16
#define CJ 256

// ---------------- K1: h = x@W, si = h.a1, sj = h.a2 ----------------
__global__ __launch_bounds__(256) void k1_hproj(const float* __restrict__ x,
                                                const float* __restrict__ W,
                                                const float* __restrict__ a,
                                                float* __restrict__ h,
                                                float* __restrict__ si,
                                                float* __restrict__ sj) {
    __shared__ float Wl[IND * OUTD];   // 32 KB = 8192 floats = 2048 float4
    __shared__ float xl[16][IND];      // 8 KB
    int t = threadIdx.x, lane = t & 63, wave = t >> 6;

    // stage W: 2048 float4, 8 per thread
    const float4* W4 = (const float4*)W;
    float4* Wl4 = (float4*)Wl;
    #pragma unroll
    for (int q = 0; q < 8; ++q) Wl4[t + q * 256] = W4[t + q * 256];

    // stage 16 x rows (2048 floats, 512 float4)
    size_t row0 = (size_t)blockIdx.x * 16;
    const float4* x4 = (const float4*)(x + row0 * IND);
    float4* xl4 = (float4*)&xl[0][0];
    xl4[t] = x4[t];
    xl4[t + 256] = x4[t + 256];
    __syncthreads();

    float a1v = a[lane];
    float a2v = a[OUTD + lane];

    float acc[4] = {0.f, 0.f, 0.f, 0.f};
    int rbase = wave * 4;
    for (int k = 0; k < IND; k += 4) {
        float4 xv0 = *(const float4*)&xl[rbase + 0][k];
        float4 xv1 = *(const float4*)&xl[rbase + 1][k];
        float4 xv2 = *(const float4*)&xl[rbase + 2][k];
        float4 xv3 = *(const float4*)&xl[rbase + 3][k];
        #pragma unroll
        for (int q = 0; q < 4; ++q) {
            float w = Wl[(k + q) * OUTD + lane];
            float xq0 = ((const float*)&xv0)[q];
            float xq1 = ((const float*)&xv1)[q];
            float xq2 = ((const float*)&xv2)[q];
            float xq3 = ((const float*)&xv3)[q];
            acc[0] = fmaf(xq0, w, acc[0]);
            acc[1] = fmaf(xq1, w, acc[1]);
            acc[2] = fmaf(xq2, w, acc[2]);
            acc[3] = fmaf(xq3, w, acc[3]);
        }
    }
    #pragma unroll
    for (int rr = 0; rr < 4; ++rr) {
        size_t grow = row0 + rbase + rr;
        h[grow * OUTD + lane] = acc[rr];
        float v1 = acc[rr] * a1v;
        float v2 = acc[rr] * a2v;
        #pragma unroll
        for (int o = 32; o; o >>= 1) {
            v1 += __shfl_xor(v1, o);
            v2 += __shfl_xor(v2, o);
        }
        if (lane == 0) { si[grow] = v1; sj[grow] = v2; }
    }
}

// ---------------- K2: row sums of exp(leaky(si+sj)) over edges + bitmask ----
__global__ __launch_bounds__(256) void k2_sums(const int* __restrict__ adj,
                                               const float* __restrict__ si,
                                               const float* __restrict__ sj,
                                               float* __restrict__ invS,
                                               unsigned char* __restrict__ mask) {
    __shared__ float wsum[4];
    int row = blockIdx.x;            // b*N + i
    int b = row >> 11;               // N = 2048
    int t = threadIdx.x, lane = t & 63, wave = t >> 6;

    float s_i = si[row];
    const int4* arow = (const int4*)(adj + (size_t)row * NN);
    int4 A0 = arow[2 * t];
    int4 A1 = arow[2 * t + 1];
    const float4* sjb = (const float4*)(sj + (size_t)b * NN);
    float4 S0 = sjb[2 * t];
    float4 S1 = sjb[2 * t + 1];

    int av[8] = {A0.x, A0.y, A0.z, A0.w, A1.x, A1.y, A1.z, A1.w};
    float sv[8] = {S0.x, S0.y, S0.z, S0.w, S1.x, S1.y, S1.z, S1.w};

    unsigned m = 0;
    float sum = 0.f;
    #pragma unroll
    for (int q = 0; q < 8; ++q) {
        float e = s_i + sv[q];
        e = e > 0.f ? e : ALPHA * e;
        float p = __expf(e);
        if (av[q] > 0) { m |= (1u << q); sum += p; }
    }
    mask[(size_t)row * 256 + t] = (unsigned char)m;

    #pragma unroll
    for (int o = 32; o; o >>= 1) sum += __shfl_xor(sum, o);
    if (lane == 0) wsum[wave] = sum;
    __syncthreads();
    if (t == 0) {
        float s = wsum[0] + wsum[1] + wsum[2] + wsum[3];
        invS[row] = s > 0.f ? 1.0f / s : 0.f;
    }
}

// ---------------- K3: attention write + h_prime = attn @ h ----------------
// Register-tiled PV: lane owns (d-quad dq = lane&15, j-window jj = lane>>6..)
//   wave g covers j in [c*CJ + g*64, +64); lane's window = 16 j's (jj = lane>>4).
//   h window staged in 64 VGPRs once per chunk; per r only 4 ds_read_b128 of p
//   feed 64 FMAs (FMA:LDS = 16:1, VALU-bound instead of LDS-bound).
__global__ __launch_bounds__(256) void k3_attn_pv(const unsigned char* __restrict__ mask,
                                                  const float* __restrict__ si,
                                                  const float* __restrict__ sj,
                                                  const float* __restrict__ invS,
                                                  const float* __restrict__ h,
                                                  float* __restrict__ attn,
                                                  float* __restrict__ hp) {
    __shared__ float p_lds[TI][CJ];        // 16 KB
    __shared__ float red[4][TI][OUTD];     // 16 KB
    __shared__ float si_s[TI], inv_s[TI];

    int t = threadIdx.x;
    int blk = blockIdx.x;                  // B * (N/TI)
    int b = blk / (NN / TI);
    int i0 = (blk % (NN / TI)) * TI;
    size_t rowbase = (size_t)b * NN + i0;

    if (t < TI) {
        si_s[t] = si[rowbase + t];
        inv_s[t] = invS[rowbase + t];
    }
    __syncthreads();

    int g = t >> 6;            // wave 0..3
    int lane = t & 63;
    int dq = lane & 15;        // d0 = dq*4
    int jj = lane >> 4;        // 0..3 (16-j sub-window within wave's 64)

    float acc[TI][4];
    #pragma unroll
    for (int r = 0; r < TI; ++r)
        #pragma unroll
        for (int q = 0; q < 4; ++q) acc[r][q] = 0.f;

    for (int c = 0; c < NN / CJ; ++c) {
        // ---- phase A: compute p for 16 rows at column j, write attn + LDS ----
        int j = c * CJ + t;
        float sjv = sj[(size_t)b * NN + j];
        int mbyte_off = j >> 3;
        int mbit = j & 7;
        #pragma unroll
        for (int r = 0; r < TI; ++r) {
            unsigned char mb = mask[(rowbase + r) * 256 + mbyte_off];
            float e = si_s[r] + sjv;
            e = e > 0.f ? e : ALPHA * e;
            float p = ((mb >> mbit) & 1) ? __expf(e) * inv_s[r] : 0.f;
            attn[(rowbase + r) * (size_t)NN + j] = p;
            p_lds[r][t] = p;
        }
        __syncthreads();

        // ---- phase B: PV. Stage h window (16 j x 4 d) in registers ----
        int jw = c * CJ + g * 64 + jj * 16;
        const float4* hb = (const float4*)(h + ((size_t)b * NN + jw) * OUTD) + dq;
        float4 hreg[16];
        #pragma unroll
        for (int k = 0; k < 16; ++k) hreg[k] = hb[(size_t)k * (OUTD / 4)];

        int pbase = g * 64 + jj * 16;
        #pragma unroll
        for (int r = 0; r < TI; ++r) {
            float pk[16];
            *(float4*)&pk[0]  = *(const float4*)&p_lds[r][pbase + 0];
            *(float4*)&pk[4]  = *(const float4*)&p_lds[r][pbase + 4];
            *(float4*)&pk[8]  = *(const float4*)&p_lds[r][pbase + 8];
            *(float4*)&pk[12] = *(const float4*)&p_lds[r][pbase + 12];
            #pragma unroll
            for (int k = 0; k < 16; ++k) {
                acc[r][0] = fmaf(pk[k], hreg[k].x, acc[r][0]);
                acc[r][1] = fmaf(pk[k], hreg[k].y, acc[r][1]);
                acc[r][2] = fmaf(pk[k], hreg[k].z, acc[r][2]);
                acc[r][3] = fmaf(pk[k], hreg[k].w, acc[r][3]);
            }
        }
        __syncthreads();
    }

    // ---- reduce over jj (lanes differing in bits 4,5) ----
    #pragma unroll
    for (int r = 0; r < TI; ++r) {
        #pragma unroll
        for (int q = 0; q < 4; ++q) {
            float v = acc[r][q];
            v += __shfl_xor(v, 16);
            v += __shfl_xor(v, 32);
            acc[r][q] = v;
        }
    }
    // lanes with jj==0 write their wave's partial (16 dq x 4 = 64 dims x 16 r)
    if (jj == 0) {
        #pragma unroll
        for (int r = 0; r < TI; ++r) {
            *(float4*)&red[g][r][dq * 4] =
                make_float4(acc[r][0], acc[r][1], acc[r][2], acc[r][3]);
        }
    }
    __syncthreads();

    // ---- cross-wave reduce + store hp ----
    for (int idx = t; idx < TI * OUTD; idx += 256) {
        int r = idx >> 6, dd = idx & 63;
        float v = red[0][r][dd] + red[1][r][dd] + red[2][r][dd] + red[3][r][dd];
        hp[(rowbase + r) * OUTD + dd] = v;
    }
}

extern "C" void kernel_launch(void* const* d_in, const int* in_sizes, int n_in,
                              void* d_out, int out_size, void* d_ws, size_t ws_size,
                              hipStream_t stream) {
    const float* x   = (const float*)d_in[0];
    const int*   adj = (const int*)d_in[1];
    const float* W   = (const float*)d_in[2];
    const float* a   = (const float*)d_in[3];

    float* out  = (float*)d_out;
    float* hp   = out;                                  // (B,N,OUT)
    float* attn = out + (size_t)BB * NN * OUTD;         // (B,N,N)

    char* ws = (char*)d_ws;
    float* h    = (float*)ws;                           // B*N*OUT floats (4 MB)
    float* si   = h + (size_t)BB * NN * OUTD;           // B*N
    float* sj   = si + (size_t)BB * NN;                 // B*N
    float* invS = sj + (size_t)BB * NN;                 // B*N
    unsigned char* mask = (unsigned char*)(invS + (size_t)BB * NN);  // B*N*256 bytes (4 MB)

    k1_hproj<<<BB * NN / 16, 256, 0, stream>>>(x, W, a, h, si, sj);
    k2_sums<<<BB * NN, 256, 0, stream>>>(adj, si, sj, invS, mask);
    k3_attn_pv<<<BB * (NN / TI), 256, 0, stream>>>(mask, si, sj, invS, h, attn, hp);
}

// Round 4
// 130.598 us; speedup vs baseline: 1.5155x; 1.3962x over previous
//
#include <hip/hip_runtime.h>

#define BB 8
#define NN 2048
#define IND 128
#define OUTD 64
#define ALPHA 0.2f

typedef __attribute__((ext_vector_type(8))) short bf16x8;
typedef __attribute__((ext_vector_type(4))) float f32x4;
typedef unsigned int u32;

// ---------------- K1: h = x@W -> h_T (bf16 hi/lo, [B][64][2048]), si, sj ----
__global__ __launch_bounds__(256) void k1_hproj(const float* __restrict__ x,
                                                const float* __restrict__ W,
                                                const float* __restrict__ a,
                                                short* __restrict__ hT_hi,
                                                short* __restrict__ hT_lo,
                                                float* __restrict__ si,
                                                float* __restrict__ sj) {
    __shared__ float Wl[IND * OUTD];     // 32 KB
    __shared__ float xl[16][IND];        // 8 KB
    __shared__ float tile[16][OUTD + 1]; // h tile for transpose (pad 65)
    int t = threadIdx.x, lane = t & 63, wave = t >> 6;

    const float4* W4 = (const float4*)W;
    float4* Wl4 = (float4*)Wl;
    #pragma unroll
    for (int q = 0; q < 8; ++q) Wl4[t + q * 256] = W4[t + q * 256];

    int row0 = blockIdx.x * 16;                    // global row in [0, B*N)
    const float4* x4 = (const float4*)(x + (size_t)row0 * IND);
    float4* xl4 = (float4*)&xl[0][0];
    xl4[t] = x4[t];
    xl4[t + 256] = x4[t + 256];
    __syncthreads();

    float a1v = a[lane];
    float a2v = a[OUTD + lane];

    float acc[4] = {0.f, 0.f, 0.f, 0.f};
    int rbase = wave * 4;
    for (int k = 0; k < IND; k += 4) {
        float4 xv0 = *(const float4*)&xl[rbase + 0][k];
        float4 xv1 = *(const float4*)&xl[rbase + 1][k];
        float4 xv2 = *(const float4*)&xl[rbase + 2][k];
        float4 xv3 = *(const float4*)&xl[rbase + 3][k];
        #pragma unroll
        for (int q = 0; q < 4; ++q) {
            float w = Wl[(k + q) * OUTD + lane];
            acc[0] = fmaf(((const float*)&xv0)[q], w, acc[0]);
            acc[1] = fmaf(((const float*)&xv1)[q], w, acc[1]);
            acc[2] = fmaf(((const float*)&xv2)[q], w, acc[2]);
            acc[3] = fmaf(((const float*)&xv3)[q], w, acc[3]);
        }
    }
    #pragma unroll
    for (int rr = 0; rr < 4; ++rr) {
        size_t grow = (size_t)row0 + rbase + rr;
        tile[rbase + rr][lane] = acc[rr];
        float v1 = acc[rr] * a1v;
        float v2 = acc[rr] * a2v;
        #pragma unroll
        for (int o = 32; o; o >>= 1) {
            v1 += __shfl_xor(v1, o);
            v2 += __shfl_xor(v2, o);
        }
        if (lane == 0) { si[grow] = v1; sj[grow] = v2; }
    }
    __syncthreads();

    // transpose + bf16 hi/lo split: thread t -> d = t>>2, k-quad = (t&3)*4
    int d = t >> 2, kq = (t & 3) * 4;
    int b = row0 >> 11;                // batch
    int krow = (row0 & (NN - 1)) + kq; // k index within batch
    float v0 = tile[kq + 0][d], v1 = tile[kq + 1][d];
    float v2 = tile[kq + 2][d], v3 = tile[kq + 3][d];
    u32 b0 = __float_as_uint(v0), b1 = __float_as_uint(v1);
    u32 b2 = __float_as_uint(v2), b3 = __float_as_uint(v3);
    u32 h0 = b0 & 0xffff0000u, h1 = b1 & 0xffff0000u;
    u32 h2 = b2 & 0xffff0000u, h3 = b3 & 0xffff0000u;
    float l0 = v0 - __uint_as_float(h0), l1 = v1 - __uint_as_float(h1);
    float l2 = v2 - __uint_as_float(h2), l3 = v3 - __uint_as_float(h3);
    uint2 hi2, lo2;
    hi2.x = (b0 >> 16) | h1;
    hi2.y = (b2 >> 16) | h3;
    lo2.x = (__float_as_uint(l0) >> 16) | (__float_as_uint(l1) & 0xffff0000u);
    lo2.y = (__float_as_uint(l2) >> 16) | (__float_as_uint(l3) & 0xffff0000u);
    size_t off = ((size_t)b * OUTD + d) * NN + krow;   // in shorts (8B aligned)
    *(uint2*)(hT_hi + off) = hi2;
    *(uint2*)(hT_lo + off) = lo2;
}

// ---------------- K23: fused {adj read + denom} + {attn write + MFMA PV} ----
__global__ __launch_bounds__(256) void k23(const int* __restrict__ adj,
                                           const float* __restrict__ si,
                                           const float* __restrict__ sj,
                                           const short* __restrict__ hT_hi,
                                           const short* __restrict__ hT_lo,
                                           float* __restrict__ attn,
                                           float* __restrict__ hp) {
    __shared__ unsigned char mask_lds[16][264];  // padded: stride 66 words
    __shared__ float inv_lds[16];
    __shared__ f32x4 red[4][4][64];              // [wave][n-tile][lane]

    int t = threadIdx.x, lane = t & 63, w = t >> 6;
    int bk = blockIdx.x;
    int b = bk >> 7;                 // 128 blocks per batch
    int i0 = (bk & 127) * 16;
    size_t rowbase = (size_t)b * NN + i0;
    const float* sjb = sj + (size_t)b * NN;

    // ---- phase 1: adj -> bitmask (LDS) + per-row denom; wave w owns 4 rows
    for (int rr = 0; rr < 4; ++rr) {
        int row = w * 4 + rr;
        size_t grow = rowbase + row;
        float s_i = si[grow];
        const int4* arow = (const int4*)(adj + grow * NN);
        float sum = 0.f;
        #pragma unroll
        for (int pass = 0; pass < 4; ++pass) {
            int jb = pass * 512 + lane * 8;
            int4 a0 = arow[pass * 128 + lane * 2];
            int4 a1 = arow[pass * 128 + lane * 2 + 1];
            float4 s0 = *(const float4*)(sjb + jb);
            float4 s1 = *(const float4*)(sjb + jb + 4);
            int av[8] = {a0.x, a0.y, a0.z, a0.w, a1.x, a1.y, a1.z, a1.w};
            float sv[8] = {s0.x, s0.y, s0.z, s0.w, s1.x, s1.y, s1.z, s1.w};
            unsigned mb = 0;
            #pragma unroll
            for (int q = 0; q < 8; ++q) {
                float e = s_i + sv[q];
                e = e > 0.f ? e : ALPHA * e;
                float pe = __expf(e);
                if (av[q] > 0) { mb |= 1u << q; sum += pe; }
            }
            mask_lds[row][pass * 64 + lane] = (unsigned char)mb;
        }
        #pragma unroll
        for (int o = 32; o; o >>= 1) sum += __shfl_xor(sum, o);
        if (lane == 0) inv_lds[row] = sum > 0.f ? 1.0f / sum : 0.f;
    }
    __syncthreads();

    // ---- phase 2: per wave, disjoint K-range of 512; no barriers inside ----
    int m = lane & 15, g = lane >> 4;
    float si_m = si[rowbase + m];
    float inv_m = inv_lds[m];
    float* arow_out = attn + (rowbase + m) * (size_t)NN;
    const short* bh_base = hT_hi + ((size_t)b * OUTD + m) * NN;
    const short* bl_base = hT_lo + ((size_t)b * OUTD + m) * NN;

    f32x4 acc[4];
    #pragma unroll
    for (int tt = 0; tt < 4; ++tt) acc[tt] = (f32x4){0.f, 0.f, 0.f, 0.f};

    for (int step = 0; step < 16; ++step) {
        int jb = w * 512 + step * 32 + g * 8;
        float4 s0 = *(const float4*)(sjb + jb);
        float4 s1 = *(const float4*)(sjb + jb + 4);
        unsigned mb = mask_lds[m][jb >> 3];
        float sv[8] = {s0.x, s0.y, s0.z, s0.w, s1.x, s1.y, s1.z, s1.w};
        float p[8];
        #pragma unroll
        for (int q = 0; q < 8; ++q) {
            float e = si_m + sv[q];
            e = e > 0.f ? e : ALPHA * e;
            float pe = __expf(e) * inv_m;
            p[q] = ((mb >> q) & 1) ? pe : 0.f;
        }
        *(float4*)(arow_out + jb) = make_float4(p[0], p[1], p[2], p[3]);
        *(float4*)(arow_out + jb + 4) = make_float4(p[4], p[5], p[6], p[7]);

        // split p into bf16 hi/lo (truncation; lo = p - hi is exact)
        union { bf16x8 v; u32 u[4]; } ph, pl;
        #pragma unroll
        for (int q = 0; q < 4; ++q) {
            u32 c0 = __float_as_uint(p[2 * q]), c1 = __float_as_uint(p[2 * q + 1]);
            u32 t0 = c0 & 0xffff0000u, t1 = c1 & 0xffff0000u;
            float d0 = p[2 * q] - __uint_as_float(t0);
            float d1 = p[2 * q + 1] - __uint_as_float(t1);
            ph.u[q] = (c0 >> 16) | t1;
            pl.u[q] = (__float_as_uint(d0) >> 16) | (__float_as_uint(d1) & 0xffff0000u);
        }

        #pragma unroll
        for (int tt = 0; tt < 4; ++tt) {
            bf16x8 bh = *(const bf16x8*)(bh_base + (size_t)tt * 16 * NN + jb);
            bf16x8 bl = *(const bf16x8*)(bl_base + (size_t)tt * 16 * NN + jb);
            acc[tt] = __builtin_amdgcn_mfma_f32_16x16x32_bf16(ph.v, bh, acc[tt], 0, 0, 0);
            acc[tt] = __builtin_amdgcn_mfma_f32_16x16x32_bf16(ph.v, bl, acc[tt], 0, 0, 0);
            acc[tt] = __builtin_amdgcn_mfma_f32_16x16x32_bf16(pl.v, bh, acc[tt], 0, 0, 0);
        }
    }

    // ---- cross-wave reduce of D (16 rows x 64 dims) ----
    #pragma unroll
    for (int tt = 0; tt < 4; ++tt) red[w][tt][lane] = acc[tt];
    __syncthreads();

    for (int idx = t; idx < 16 * OUTD; idx += 256) {
        int row = idx >> 6, n = idx & 63;
        int ln = (row >> 2) * 16 + (n & 15);
        int reg = row & 3;
        float v = ((const float*)&red[0][n >> 4][ln])[reg]
                + ((const float*)&red[1][n >> 4][ln])[reg]
                + ((const float*)&red[2][n >> 4][ln])[reg]
                + ((const float*)&red[3][n >> 4][ln])[reg];
        hp[(rowbase + row) * OUTD + n] = v;
    }
}

extern "C" void kernel_launch(void* const* d_in, const int* in_sizes, int n_in,
                              void* d_out, int out_size, void* d_ws, size_t ws_size,
                              hipStream_t stream) {
    const float* x   = (const float*)d_in[0];
    const int*   adj = (const int*)d_in[1];
    const float* W   = (const float*)d_in[2];
    const float* a   = (const float*)d_in[3];

    float* out  = (float*)d_out;
    float* hp   = out;                                  // (B,N,OUT)
    float* attn = out + (size_t)BB * NN * OUTD;         // (B,N,N)

    char* ws = (char*)d_ws;
    short* hT_hi = (short*)ws;                           // B*64*2048 shorts (2 MB)
    short* hT_lo = hT_hi + (size_t)BB * OUTD * NN;       // 2 MB
    float* si    = (float*)(hT_lo + (size_t)BB * OUTD * NN);
    float* sj    = si + (size_t)BB * NN;

    k1_hproj<<<BB * NN / 16, 256, 0, stream>>>(x, W, a, hT_hi, hT_lo, si, sj);
    k23<<<BB * NN / 16, 256, 0, stream>>>(adj, si, sj, hT_hi, hT_lo, attn, hp);
}